// Round 5
// baseline (338.201 us; speedup 1.0000x reference)
//
#include <hip/hip_runtime.h>
#include <hip/hip_fp16.h>
#include <math.h>

#define BATCH 8
#define CIN   256
#define COUT  256
#define HH    64
#define WW    64
#define K2    9
#define CKTOT (CIN*K2)       // 2304
#define NPIX  (HH*WW)        // 4096
#define PB    32             // positions per block (half row; same b,y)
#define CCH   32             // channels per chunk
#define NCH   (CIN/CCH)      // 8 chunks
#define ROWBLK 40            // 16B-blocks per smp row (36 used + pad; XOR stays < 40)
#define INV_STRIDE 0.125f

typedef __attribute__((ext_vector_type(8))) short bf16x8;
typedef __attribute__((ext_vector_type(4))) float f32x4;

union Pack16 { uint4 u; bf16x8 v; };

__device__ __forceinline__ unsigned bf16rne(float f) {
    union { float f; unsigned u; } a; a.f = f;
    return (a.u + 0x7FFFu + ((a.u >> 16) & 1u)) >> 16;
}
__device__ __forceinline__ float bflo(unsigned u) {
    union { unsigned u; float f; } a; a.u = u << 16; return a.f;
}
__device__ __forceinline__ float bfhi(unsigned u) {
    union { unsigned u; float f; } a; a.u = u & 0xFFFF0000u; return a.f;
}

// ---- Kernel W: w[o][c*9+kk] -> wbf[o][kk*256+c] bf16, one o per block, LDS relayout ----
__global__ __launch_bounds__(256) void convert_w(const float* __restrict__ w,
                                                 ushort* __restrict__ wbf) {
    __shared__ ushort ls[CKTOT];
    const int o = blockIdx.x;
    const float* __restrict__ wo = w + (size_t)o * CKTOT;
    #pragma unroll
    for (int m = 0; m < 9; ++m)
        ls[m * 256 + threadIdx.x] = (ushort)bf16rne(wo[m * 256 + threadIdx.x]);
    __syncthreads();
    ushort* __restrict__ op = wbf + (size_t)o * CKTOT;
    #pragma unroll
    for (int m = 0; m < 9; ++m) {
        int dst = m * 256 + threadIdx.x;     // = kk*256 + c
        int kk = dst >> 8, c = dst & 255;
        op[dst] = ls[c * 9 + kk];
    }
}

// ---- Kernel T: x NCHW f32 -> xt NHWC bf16 (float4 reads, uint writes) ----
__global__ __launch_bounds__(256) void transpose_x(const float* __restrict__ x,
                                                   ushort* __restrict__ xt) {
    __shared__ ushort tile[WW][CIN + 2];
    const int by  = blockIdx.x;                  // b*64 + y
    const int tid = threadIdx.x;
    const float* __restrict__ xp = x + (size_t)(by >> 6) * CIN * NPIX + (size_t)(by & 63) * WW;
    #pragma unroll 4
    for (int pass = 0; pass < 16; ++pass) {      // c = pass*16 + tid>>4 ; x = (tid&15)*4
        int c  = pass * 16 + (tid >> 4);
        int x4 = (tid & 15) * 4;
        float4 v = *(const float4*)(xp + (size_t)c * NPIX + x4);
        tile[x4 + 0][c] = (ushort)bf16rne(v.x);
        tile[x4 + 1][c] = (ushort)bf16rne(v.y);
        tile[x4 + 2][c] = (ushort)bf16rne(v.z);
        tile[x4 + 3][c] = (ushort)bf16rne(v.w);
    }
    __syncthreads();
    ushort* __restrict__ op = xt + (size_t)by * WW * CIN;
    #pragma unroll 4
    for (int pass = 0; pass < 32; ++pass) {      // r = pass*2 + tid>>7 ; c2 = (tid&127)*2
        int r  = pass * 2 + (tid >> 7);
        int c2 = (tid & 127) * 2;
        uint v = (uint)tile[r][c2] | ((uint)tile[r][c2 + 1] << 16);
        *(uint*)(op + (size_t)r * CIN + c2) = v;
    }
}

__device__ __forceinline__ uint4 combine4(uint4 c0, uint4 c1, uint4 c2, uint4 c3,
                                          float w0, float w1, float w2, float w3) {
    const uint u0[4] = {c0.x, c0.y, c0.z, c0.w};
    const uint u1[4] = {c1.x, c1.y, c1.z, c1.w};
    const uint u2[4] = {c2.x, c2.y, c2.z, c2.w};
    const uint u3[4] = {c3.x, c3.y, c3.z, c3.w};
    uint pk[4];
    #pragma unroll
    for (int q = 0; q < 4; ++q) {
        float slo = w0 * bflo(u0[q]) + w1 * bflo(u1[q]) + w2 * bflo(u2[q]) + w3 * bflo(u3[q]);
        float shi = w0 * bfhi(u0[q]) + w1 * bfhi(u1[q]) + w2 * bfhi(u2[q]) + w3 * bfhi(u3[q]);
        pk[q] = bf16rne(slo) | (bf16rne(shi) << 16);
    }
    return make_uint4(pk[0], pk[1], pk[2], pk[3]);
}

// ---- Kernel B: offset + NHWC gather (4-deep pipelined, issue-early) + MFMA + relu ----
__global__ __launch_bounds__(256, 4) void align_conv(const ushort* __restrict__ xt,
                                                     const float* __restrict__ anchors,
                                                     const ushort* __restrict__ wbf,
                                                     float* __restrict__ out) {
    __shared__ uint4   smp[PB * ROWBLK];         // 20 KB
    __shared__ ushort4 midx[PB * K2];            // 2.25 KB
    __shared__ ushort4 mwh [PB * K2];            // 2.25 KB

    const int tid = threadIdx.x;
    const int bid = blockIdx.x;
    const int swz = (bid & 7) * 128 + (bid >> 3);   // XCD-chunked: each XCD owns one batch image
    const int g0  = swz * PB;
    const int b   = g0 >> 12;
    const int l0  = g0 & 4095;
    const int y   = l0 >> 6;
    const int xb0 = l0 & 63;                        // 0 or 32
    const ushort* __restrict__ xtb = xt + (size_t)b * NPIX * CIN;

    // ---- phase 0: bilinear metadata (32 pos x 9 taps) ----
    for (int i = tid; i < PB * K2; i += 256) {
        int p = i / 9;
        int k = i - p * 9;
        const float* a = anchors + ((size_t)b * 4096 + l0 + p) * 5;
        float xc = a[0] * INV_STRIDE;
        float yc = a[1] * INV_STRIDE;
        float dw = (a[2] * INV_STRIDE) * (1.f / 3.f);
        float dh = (a[3] * INV_STRIDE) * (1.f / 3.f);
        float ang = a[4];
        float cs = cosf(ang), sn = sinf(ang);
        float kxf = (float)(k % 3 - 1);
        float kyf = (float)(k / 3 - 1);
        float xk = dw * kxf, yk = dh * kyf;
        float px = cs * xk - sn * yk + xc;
        float py = sn * xk + cs * yk + yc;

        float x0f = floorf(px), y0f = floorf(py);
        float wx1 = px - x0f,   wy1 = py - y0f;
        float wx0 = 1.f - wx1,  wy0 = 1.f - wy1;
        int x0 = (int)x0f, y0 = (int)y0f;
        int x1 = x0 + 1,   y1 = y0 + 1;
        bool vx0 = (x0 >= 0) & (x0 < WW);
        bool vx1 = (x1 >= 0) & (x1 < WW);
        bool vy0 = (y0 >= 0) & (y0 < HH);
        bool vy1 = (y1 >= 0) & (y1 < HH);
        int xc0 = min(max(x0, 0), WW - 1);
        int xc1 = min(max(x1, 0), WW - 1);
        int yc0 = min(max(y0, 0), HH - 1);
        int yc1 = min(max(y1, 0), HH - 1);
        float f0 = (vy0 & vx0) ? wy0 * wx0 : 0.f;
        float f1 = (vy0 & vx1) ? wy0 * wx1 : 0.f;
        float f2 = (vy1 & vx0) ? wy1 * wx0 : 0.f;
        float f3 = (vy1 & vx1) ? wy1 * wx1 : 0.f;
        midx[i] = make_ushort4((ushort)(yc0 * WW + xc0), (ushort)(yc0 * WW + xc1),
                               (ushort)(yc1 * WW + xc0), (ushort)(yc1 * WW + xc1));
        mwh[i]  = make_ushort4(__half_as_ushort(__float2half(f0)),
                               __half_as_ushort(__float2half(f1)),
                               __half_as_ushort(__float2half(f2)),
                               __half_as_ushort(__float2half(f3)));
    }

    const int lane = tid & 63;
    const int wn   = tid >> 6;       // 4 waves: output quarter
    const int lr   = lane & 15;
    const int kg   = lane >> 4;

    f32x4 acc[2][4];
    #pragma unroll
    for (int mi2 = 0; mi2 < 2; ++mi2)
        #pragma unroll
        for (int ni = 0; ni < 4; ++ni)
            acc[mi2][ni] = (f32x4){0.f, 0.f, 0.f, 0.f};

    // staging pipeline registers: 4 uniform tasks + kk=8 tail on waves 0-1
    uint4 ld[4][4];
    float wv[4][4];
    int   dst[4];
    uint4 tl[4];
    float tw[4];
    int   tdst = 0;
    const bool tail = (tid < 128);

    auto ISSUE = [&](int ch) {
        #pragma unroll
        for (int j = 0; j < 4; ++j) {
            int t  = tid + j * 256;          // 0..1023
            int cb = t & 3;
            int pp = (t >> 2) & 31;
            int kk = t >> 7;
            int i  = pp * 9 + kk;
            ushort4 mi = midx[i];
            ushort4 mh = mwh[i];
            wv[j][0] = __half2float(__ushort_as_half(mh.x));
            wv[j][1] = __half2float(__ushort_as_half(mh.y));
            wv[j][2] = __half2float(__ushort_as_half(mh.z));
            wv[j][3] = __half2float(__ushort_as_half(mh.w));
            int ch0 = ch * CCH + cb * 8;
            ld[j][0] = *(const uint4*)(xtb + (size_t)mi.x * CIN + ch0);
            ld[j][1] = *(const uint4*)(xtb + (size_t)mi.y * CIN + ch0);
            ld[j][2] = *(const uint4*)(xtb + (size_t)mi.z * CIN + ch0);
            ld[j][3] = *(const uint4*)(xtb + (size_t)mi.w * CIN + ch0);
            dst[j] = pp * ROWBLK + ((kk * 4 + cb) ^ (pp & 7));
        }
        if (tail) {                          // t = 1024 + tid -> kk = 8 plane
            int cb = tid & 3;
            int pp = (tid >> 2) & 31;
            int i  = pp * 9 + 8;
            ushort4 mi = midx[i];
            ushort4 mh = mwh[i];
            tw[0] = __half2float(__ushort_as_half(mh.x));
            tw[1] = __half2float(__ushort_as_half(mh.y));
            tw[2] = __half2float(__ushort_as_half(mh.z));
            tw[3] = __half2float(__ushort_as_half(mh.w));
            int ch0 = ch * CCH + cb * 8;
            tl[0] = *(const uint4*)(xtb + (size_t)mi.x * CIN + ch0);
            tl[1] = *(const uint4*)(xtb + (size_t)mi.y * CIN + ch0);
            tl[2] = *(const uint4*)(xtb + (size_t)mi.z * CIN + ch0);
            tl[3] = *(const uint4*)(xtb + (size_t)mi.w * CIN + ch0);
            tdst = pp * ROWBLK + ((32 + cb) ^ (pp & 7));
        }
    };
    auto COMBINE = [&]() {
        #pragma unroll
        for (int j = 0; j < 4; ++j)
            smp[dst[j]] = combine4(ld[j][0], ld[j][1], ld[j][2], ld[j][3],
                                   wv[j][0], wv[j][1], wv[j][2], wv[j][3]);
        if (tail)
            smp[tdst] = combine4(tl[0], tl[1], tl[2], tl[3], tw[0], tw[1], tw[2], tw[3]);
    };
    auto MFMA = [&](int ch) {
        const ushort* wbase = wbf + (size_t)(wn * 64 + lr) * CKTOT + ch * CCH + kg * 8;
        #pragma unroll 3
        for (int kk = 0; kk < 9; ++kk) {
            int blk = kk * 4 + kg;
            Pack16 a0; a0.u = smp[lr * ROWBLK + (blk ^ (lr & 7))];
            Pack16 a1; a1.u = smp[(lr + 16) * ROWBLK + (blk ^ (lr & 7))];
            const ushort* wk = wbase + kk * 256;
            bf16x8 b0 = *(const bf16x8*)(wk);
            bf16x8 b1 = *(const bf16x8*)(wk + 16 * CKTOT);
            bf16x8 b2 = *(const bf16x8*)(wk + 32 * CKTOT);
            bf16x8 b3 = *(const bf16x8*)(wk + 48 * CKTOT);
            acc[0][0] = __builtin_amdgcn_mfma_f32_16x16x32_bf16(a0.v, b0, acc[0][0], 0, 0, 0);
            acc[0][1] = __builtin_amdgcn_mfma_f32_16x16x32_bf16(a0.v, b1, acc[0][1], 0, 0, 0);
            acc[0][2] = __builtin_amdgcn_mfma_f32_16x16x32_bf16(a0.v, b2, acc[0][2], 0, 0, 0);
            acc[0][3] = __builtin_amdgcn_mfma_f32_16x16x32_bf16(a0.v, b3, acc[0][3], 0, 0, 0);
            acc[1][0] = __builtin_amdgcn_mfma_f32_16x16x32_bf16(a1.v, b0, acc[1][0], 0, 0, 0);
            acc[1][1] = __builtin_amdgcn_mfma_f32_16x16x32_bf16(a1.v, b1, acc[1][1], 0, 0, 0);
            acc[1][2] = __builtin_amdgcn_mfma_f32_16x16x32_bf16(a1.v, b2, acc[1][2], 0, 0, 0);
            acc[1][3] = __builtin_amdgcn_mfma_f32_16x16x32_bf16(a1.v, b3, acc[1][3], 0, 0, 0);
        }
    };

    __syncthreads();                 // meta ready
    ISSUE(0);
    COMBINE();
    __syncthreads();                 // smp(ch0) ready
    for (int ch = 0; ch < NCH; ++ch) {
        if (ch + 1 < NCH) ISSUE(ch + 1);   // loads fly during MFMA (T14)
        MFMA(ch);
        __syncthreads();                   // smp reads done
        if (ch + 1 < NCH) {
            COMBINE();
            __syncthreads();               // smp(ch+1) ready
        }
    }

    // ---- epilogue: relu + float4 stores ----
    #pragma unroll
    for (int mi2 = 0; mi2 < 2; ++mi2) {
        int xo = xb0 + mi2 * 16 + kg * 4;
        #pragma unroll
        for (int ni = 0; ni < 4; ++ni) {
            int o = wn * 64 + ni * 16 + lr;
            float4 v;
            v.x = fmaxf(acc[mi2][ni][0], 0.f);
            v.y = fmaxf(acc[mi2][ni][1], 0.f);
            v.z = fmaxf(acc[mi2][ni][2], 0.f);
            v.w = fmaxf(acc[mi2][ni][3], 0.f);
            *(float4*)&out[(((size_t)b * COUT + o) * HH + y) * WW + xo] = v;
        }
    }
}

extern "C" void kernel_launch(void* const* d_in, const int* in_sizes, int n_in,
                              void* d_out, int out_size, void* d_ws, size_t ws_size,
                              hipStream_t stream) {
    const float* x       = (const float*)d_in[0];
    const float* anchors = (const float*)d_in[1];
    const float* w       = (const float*)d_in[2];
    ushort* xt  = (ushort*)d_ws;                                            // 16 MB
    ushort* wbf = (ushort*)((char*)d_ws + (size_t)BATCH * NPIX * CIN * 2);  // 1.18 MB
    float* out  = (float*)d_out;

    hipLaunchKernelGGL(transpose_x, dim3(BATCH * HH), dim3(256), 0, stream, x, xt);
    hipLaunchKernelGGL(convert_w, dim3(COUT), dim3(256), 0, stream, w, wbf);
    hipLaunchKernelGGL(align_conv, dim3((BATCH * HH * WW) / PB), dim3(256), 0, stream,
                       xt, anchors, wbf, out);
}

// Round 6
// 245.669 us; speedup vs baseline: 1.3767x; 1.3767x over previous
//
#include <hip/hip_runtime.h>
#include <hip/hip_fp16.h>
#include <math.h>

#define BATCH 8
#define CIN   256
#define COUT  256
#define HH    64
#define WW    64
#define K2    9
#define CKTOT (CIN*K2)       // 2304
#define NPIX  (HH*WW)        // 4096
#define PB    32             // positions per block (half row; same b,y)
#define CCH   32             // channels per chunk
#define NCH   (CIN/CCH)      // 8 chunks
#define ROWBLK 40            // 16B-blocks per smp row (36 used + pad; XOR stays < 40)
#define INV_STRIDE 0.125f

typedef __attribute__((ext_vector_type(8))) short bf16x8;
typedef __attribute__((ext_vector_type(4))) float f32x4;

union Pack16 { uint4 u; bf16x8 v; };

__device__ __forceinline__ unsigned bf16rne(float f) {
    union { float f; unsigned u; } a; a.f = f;
    return (a.u + 0x7FFFu + ((a.u >> 16) & 1u)) >> 16;
}
__device__ __forceinline__ float bflo(unsigned u) {
    union { unsigned u; float f; } a; a.u = u << 16; return a.f;
}
__device__ __forceinline__ float bfhi(unsigned u) {
    union { unsigned u; float f; } a; a.u = u & 0xFFFF0000u; return a.f;
}

// ---- Kernel W: w[o][c*9+kk] -> wbf[o][kk*256+c] bf16, one o per block, LDS relayout ----
__global__ __launch_bounds__(256) void convert_w(const float* __restrict__ w,
                                                 ushort* __restrict__ wbf) {
    __shared__ ushort ls[CKTOT];
    const int o = blockIdx.x;
    const float* __restrict__ wo = w + (size_t)o * CKTOT;
    #pragma unroll
    for (int m = 0; m < 9; ++m)
        ls[m * 256 + threadIdx.x] = (ushort)bf16rne(wo[m * 256 + threadIdx.x]);
    __syncthreads();
    ushort* __restrict__ op = wbf + (size_t)o * CKTOT;
    #pragma unroll
    for (int m = 0; m < 9; ++m) {
        int dst = m * 256 + threadIdx.x;     // = kk*256 + c
        int kk = dst >> 8, c = dst & 255;
        op[dst] = ls[c * 9 + kk];
    }
}

// ---- Kernel T: x NCHW f32 -> xt NHWC bf16 (float4 reads, uint writes) ----
__global__ __launch_bounds__(256) void transpose_x(const float* __restrict__ x,
                                                   ushort* __restrict__ xt) {
    __shared__ ushort tile[WW][CIN + 2];
    const int by  = blockIdx.x;                  // b*64 + y
    const int tid = threadIdx.x;
    const float* __restrict__ xp = x + (size_t)(by >> 6) * CIN * NPIX + (size_t)(by & 63) * WW;
    #pragma unroll 4
    for (int pass = 0; pass < 16; ++pass) {      // c = pass*16 + tid>>4 ; x = (tid&15)*4
        int c  = pass * 16 + (tid >> 4);
        int x4 = (tid & 15) * 4;
        float4 v = *(const float4*)(xp + (size_t)c * NPIX + x4);
        tile[x4 + 0][c] = (ushort)bf16rne(v.x);
        tile[x4 + 1][c] = (ushort)bf16rne(v.y);
        tile[x4 + 2][c] = (ushort)bf16rne(v.z);
        tile[x4 + 3][c] = (ushort)bf16rne(v.w);
    }
    __syncthreads();
    ushort* __restrict__ op = xt + (size_t)by * WW * CIN;
    #pragma unroll 4
    for (int pass = 0; pass < 32; ++pass) {      // r = pass*2 + tid>>7 ; c2 = (tid&127)*2
        int r  = pass * 2 + (tid >> 7);
        int c2 = (tid & 127) * 2;
        uint v = (uint)tile[r][c2] | ((uint)tile[r][c2 + 1] << 16);
        *(uint*)(op + (size_t)r * CIN + c2) = v;
    }
}

__device__ __forceinline__ uint4 combine4(uint4 c0, uint4 c1, uint4 c2, uint4 c3,
                                          float w0, float w1, float w2, float w3) {
    const uint u0[4] = {c0.x, c0.y, c0.z, c0.w};
    const uint u1[4] = {c1.x, c1.y, c1.z, c1.w};
    const uint u2[4] = {c2.x, c2.y, c2.z, c2.w};
    const uint u3[4] = {c3.x, c3.y, c3.z, c3.w};
    uint pk[4];
    #pragma unroll
    for (int q = 0; q < 4; ++q) {
        float slo = w0 * bflo(u0[q]) + w1 * bflo(u1[q]) + w2 * bflo(u2[q]) + w3 * bflo(u3[q]);
        float shi = w0 * bfhi(u0[q]) + w1 * bfhi(u1[q]) + w2 * bfhi(u2[q]) + w3 * bfhi(u3[q]);
        pk[q] = bf16rne(slo) | (bf16rne(shi) << 16);
    }
    return make_uint4(pk[0], pk[1], pk[2], pk[3]);
}

// ---- Kernel B: offset + NHWC gather (immediate combine, unrolled) + MFMA + relu ----
__global__ __launch_bounds__(256, 4) void align_conv(const ushort* __restrict__ xt,
                                                     const float* __restrict__ anchors,
                                                     const ushort* __restrict__ wbf,
                                                     float* __restrict__ out) {
    __shared__ uint4   smp[PB * ROWBLK];         // 20 KB
    __shared__ ushort4 midx[PB * K2];            // 2.25 KB
    __shared__ ushort4 mwh [PB * K2];            // 2.25 KB

    const int tid = threadIdx.x;
    const int bid = blockIdx.x;
    const int swz = (bid & 7) * 128 + (bid >> 3);   // XCD-chunked: each XCD owns one batch image
    const int g0  = swz * PB;
    const int b   = g0 >> 12;
    const int l0  = g0 & 4095;
    const int y   = l0 >> 6;
    const int xb0 = l0 & 63;                        // 0 or 32
    const ushort* __restrict__ xtb = xt + (size_t)b * NPIX * CIN;

    // ---- phase 0: bilinear metadata (32 pos x 9 taps) ----
    for (int i = tid; i < PB * K2; i += 256) {
        int p = i / 9;
        int k = i - p * 9;
        const float* a = anchors + ((size_t)b * 4096 + l0 + p) * 5;
        float xc = a[0] * INV_STRIDE;
        float yc = a[1] * INV_STRIDE;
        float dw = (a[2] * INV_STRIDE) * (1.f / 3.f);
        float dh = (a[3] * INV_STRIDE) * (1.f / 3.f);
        float ang = a[4];
        float cs = cosf(ang), sn = sinf(ang);
        float kxf = (float)(k % 3 - 1);
        float kyf = (float)(k / 3 - 1);
        float xk = dw * kxf, yk = dh * kyf;
        float px = cs * xk - sn * yk + xc;
        float py = sn * xk + cs * yk + yc;

        float x0f = floorf(px), y0f = floorf(py);
        float wx1 = px - x0f,   wy1 = py - y0f;
        float wx0 = 1.f - wx1,  wy0 = 1.f - wy1;
        int x0 = (int)x0f, y0 = (int)y0f;
        int x1 = x0 + 1,   y1 = y0 + 1;
        bool vx0 = (x0 >= 0) & (x0 < WW);
        bool vx1 = (x1 >= 0) & (x1 < WW);
        bool vy0 = (y0 >= 0) & (y0 < HH);
        bool vy1 = (y1 >= 0) & (y1 < HH);
        int xc0 = min(max(x0, 0), WW - 1);
        int xc1 = min(max(x1, 0), WW - 1);
        int yc0 = min(max(y0, 0), HH - 1);
        int yc1 = min(max(y1, 0), HH - 1);
        float f0 = (vy0 & vx0) ? wy0 * wx0 : 0.f;
        float f1 = (vy0 & vx1) ? wy0 * wx1 : 0.f;
        float f2 = (vy1 & vx0) ? wy1 * wx0 : 0.f;
        float f3 = (vy1 & vx1) ? wy1 * wx1 : 0.f;
        midx[i] = make_ushort4((ushort)(yc0 * WW + xc0), (ushort)(yc0 * WW + xc1),
                               (ushort)(yc1 * WW + xc0), (ushort)(yc1 * WW + xc1));
        mwh[i]  = make_ushort4(__half_as_ushort(__float2half(f0)),
                               __half_as_ushort(__float2half(f1)),
                               __half_as_ushort(__float2half(f2)),
                               __half_as_ushort(__float2half(f3)));
    }

    const int lane = tid & 63;
    const int wn   = tid >> 6;       // 4 waves: output quarter
    const int lr   = lane & 15;
    const int kg   = lane >> 4;

    f32x4 acc[2][4];
    #pragma unroll
    for (int mi2 = 0; mi2 < 2; ++mi2)
        #pragma unroll
        for (int ni = 0; ni < 4; ++ni)
            acc[mi2][ni] = (f32x4){0.f, 0.f, 0.f, 0.f};

    const bool tail = (tid < 128);

    // one staging task: load 4 corner bf16x8 rows, combine, write LDS (short live range)
    auto TASK = [&](int t, int ch) {
        int cb = t & 3;
        int pp = (t >> 2) & 31;
        int kk = t >> 7;                 // t in 0..1151 -> kk 0..8
        int i  = pp * 9 + kk;
        ushort4 mi = midx[i];
        ushort4 mh = mwh[i];
        float w0 = __half2float(__ushort_as_half(mh.x));
        float w1 = __half2float(__ushort_as_half(mh.y));
        float w2 = __half2float(__ushort_as_half(mh.z));
        float w3 = __half2float(__ushort_as_half(mh.w));
        int ch0 = ch * CCH + cb * 8;
        uint4 c0 = *(const uint4*)(xtb + (size_t)mi.x * CIN + ch0);
        uint4 c1 = *(const uint4*)(xtb + (size_t)mi.y * CIN + ch0);
        uint4 c2 = *(const uint4*)(xtb + (size_t)mi.z * CIN + ch0);
        uint4 c3 = *(const uint4*)(xtb + (size_t)mi.w * CIN + ch0);
        smp[pp * ROWBLK + ((kk * 4 + cb) ^ (pp & 7))] =
            combine4(c0, c1, c2, c3, w0, w1, w2, w3);
    };

    auto STAGE = [&](int ch) {
        #pragma unroll
        for (int j = 0; j < 4; ++j)
            TASK(tid + j * 256, ch);     // kk 0..7 planes
        if (tail)
            TASK(1024 + tid, ch);        // kk = 8 plane
    };

    auto MFMA = [&](int ch) {
        const ushort* wbase = wbf + (size_t)(wn * 64 + lr) * CKTOT + ch * CCH + kg * 8;
        __builtin_amdgcn_s_setprio(1);
        #pragma unroll 3
        for (int kk = 0; kk < 9; ++kk) {
            int blk = kk * 4 + kg;
            Pack16 a0; a0.u = smp[lr * ROWBLK + (blk ^ (lr & 7))];
            Pack16 a1; a1.u = smp[(lr + 16) * ROWBLK + (blk ^ (lr & 7))];
            const ushort* wk = wbase + kk * 256;
            bf16x8 b0 = *(const bf16x8*)(wk);
            bf16x8 b1 = *(const bf16x8*)(wk + 16 * CKTOT);
            bf16x8 b2 = *(const bf16x8*)(wk + 32 * CKTOT);
            bf16x8 b3 = *(const bf16x8*)(wk + 48 * CKTOT);
            acc[0][0] = __builtin_amdgcn_mfma_f32_16x16x32_bf16(a0.v, b0, acc[0][0], 0, 0, 0);
            acc[0][1] = __builtin_amdgcn_mfma_f32_16x16x32_bf16(a0.v, b1, acc[0][1], 0, 0, 0);
            acc[0][2] = __builtin_amdgcn_mfma_f32_16x16x32_bf16(a0.v, b2, acc[0][2], 0, 0, 0);
            acc[0][3] = __builtin_amdgcn_mfma_f32_16x16x32_bf16(a0.v, b3, acc[0][3], 0, 0, 0);
            acc[1][0] = __builtin_amdgcn_mfma_f32_16x16x32_bf16(a1.v, b0, acc[1][0], 0, 0, 0);
            acc[1][1] = __builtin_amdgcn_mfma_f32_16x16x32_bf16(a1.v, b1, acc[1][1], 0, 0, 0);
            acc[1][2] = __builtin_amdgcn_mfma_f32_16x16x32_bf16(a1.v, b2, acc[1][2], 0, 0, 0);
            acc[1][3] = __builtin_amdgcn_mfma_f32_16x16x32_bf16(a1.v, b3, acc[1][3], 0, 0, 0);
        }
        __builtin_amdgcn_s_setprio(0);
    };

    __syncthreads();                 // meta ready
    for (int ch = 0; ch < NCH; ++ch) {
        STAGE(ch);
        __syncthreads();             // smp(ch) ready
        MFMA(ch);
        __syncthreads();             // smp reads done
    }

    // ---- epilogue: relu + float4 stores ----
    #pragma unroll
    for (int mi2 = 0; mi2 < 2; ++mi2) {
        int xo = xb0 + mi2 * 16 + kg * 4;
        #pragma unroll
        for (int ni = 0; ni < 4; ++ni) {
            int o = wn * 64 + ni * 16 + lr;
            float4 v;
            v.x = fmaxf(acc[mi2][ni][0], 0.f);
            v.y = fmaxf(acc[mi2][ni][1], 0.f);
            v.z = fmaxf(acc[mi2][ni][2], 0.f);
            v.w = fmaxf(acc[mi2][ni][3], 0.f);
            *(float4*)&out[(((size_t)b * COUT + o) * HH + y) * WW + xo] = v;
        }
    }
}

extern "C" void kernel_launch(void* const* d_in, const int* in_sizes, int n_in,
                              void* d_out, int out_size, void* d_ws, size_t ws_size,
                              hipStream_t stream) {
    const float* x       = (const float*)d_in[0];
    const float* anchors = (const float*)d_in[1];
    const float* w       = (const float*)d_in[2];
    ushort* xt  = (ushort*)d_ws;                                            // 16 MB
    ushort* wbf = (ushort*)((char*)d_ws + (size_t)BATCH * NPIX * CIN * 2);  // 1.18 MB
    float* out  = (float*)d_out;

    hipLaunchKernelGGL(transpose_x, dim3(BATCH * HH), dim3(256), 0, stream, x, xt);
    hipLaunchKernelGGL(convert_w, dim3(COUT), dim3(256), 0, stream, w, wbf);
    hipLaunchKernelGGL(align_conv, dim3((BATCH * HH * WW) / PB), dim3(256), 0, stream,
                       xt, anchors, wbf, out);
}